// Round 2
// baseline (470.297 us; speedup 1.0000x reference)
//
#include <hip/hip_runtime.h>

static inline int ceil_div(int a, int b) { return (a + b - 1) / b; }

// ---------------- CSR build ----------------

__global__ void count_kernel(const int* __restrict__ ei, int* __restrict__ deg, int E) {
    int e = blockIdx.x * blockDim.x + threadIdx.x;
    if (e < E) atomicAdd(&deg[ei[E + e]], 1);   // row 1 of edge_index = dst
}

__global__ __launch_bounds__(1024) void scan_kernel(const int* __restrict__ deg,
        int* __restrict__ rowptr, float* __restrict__ dinv, int n) {
    __shared__ int partials[1024];
    int tid = threadIdx.x;
    int chunk = (n + 1023) >> 10;
    int begin = tid * chunk; if (begin > n) begin = n;
    int end = begin + chunk; if (end > n) end = n;
    int sum = 0;
    for (int i = begin; i < end; ++i) sum += deg[i];
    partials[tid] = sum;
    __syncthreads();
    // Hillis-Steele inclusive scan over 1024 partials
    for (int off = 1; off < 1024; off <<= 1) {
        int v = 0;
        if (tid >= off) v = partials[tid - off];
        __syncthreads();
        if (tid >= off) partials[tid] += v;
        __syncthreads();
    }
    int base = (tid > 0) ? partials[tid - 1] : 0;
    for (int i = begin; i < end; ++i) {
        rowptr[i] = base;
        int c = deg[i];
        dinv[i] = rsqrtf((float)(c + 1));   // +1 self-loop; deg>=1 always
        base += c;
    }
    if (tid == 1023) rowptr[n] = base;
}

__global__ void fill_kernel(const int* __restrict__ ei, const int* __restrict__ rowptr,
        int* __restrict__ cursor, int* __restrict__ colidx, int E) {
    int e = blockIdx.x * blockDim.x + threadIdx.x;
    if (e < E) {
        int s = ei[e];
        int d = ei[E + e];
        int pos = rowptr[d] + atomicAdd(&cursor[d], 1);
        colidx[pos] = s;
    }
}

// ---------------- fp32 tiled GEMM: out[M,N] = A[M,K] @ W[K,N] (+bias) ----------------

template<int K, int N, bool BIAS>
__global__ __launch_bounds__(256) void gemm_kernel(const float* __restrict__ A,
        const float* __restrict__ W, const float* __restrict__ bias,
        float* __restrict__ out, int M) {
    __shared__ float As[16][68];   // [k][m], padded
    __shared__ float Bs[16][68];   // [k][n]
    const int bm = blockIdx.x * 64;
    const int bn = blockIdx.y * 64;
    const int tid = (int)threadIdx.x;
    const int tx = tid & 15;
    const int ty = tid >> 4;
    float acc[4][4] = {};
    for (int k0 = 0; k0 < K; k0 += 16) {
        {   // A tile: 64 rows x 16 k, float4-coalesced, stored transposed
            int m   = tid >> 2;
            int kk4 = (tid & 3) * 4;
            float4 v = make_float4(0.f, 0.f, 0.f, 0.f);
            if (bm + m < M)
                v = *(const float4*)&A[(size_t)(bm + m) * K + k0 + kk4];
            As[kk4 + 0][m] = v.x;
            As[kk4 + 1][m] = v.y;
            As[kk4 + 2][m] = v.z;
            As[kk4 + 3][m] = v.w;
        }
        {   // B tile: 16 k x 64 n
            int kk = tid >> 4;
            int n4 = (tid & 15) * 4;
            *(float4*)&Bs[kk][n4] = *(const float4*)&W[(size_t)(k0 + kk) * N + bn + n4];
        }
        __syncthreads();
        #pragma unroll
        for (int kk = 0; kk < 16; ++kk) {
            float4 a4 = *(const float4*)&As[kk][ty * 4];
            float4 b4 = *(const float4*)&Bs[kk][tx * 4];
            float a[4] = {a4.x, a4.y, a4.z, a4.w};
            float b[4] = {b4.x, b4.y, b4.z, b4.w};
            #pragma unroll
            for (int i = 0; i < 4; ++i)
                #pragma unroll
                for (int j = 0; j < 4; ++j)
                    acc[i][j] += a[i] * b[j];
        }
        __syncthreads();
    }
    #pragma unroll
    for (int i = 0; i < 4; ++i) {
        int m = bm + ty * 4 + i;
        if (m >= M) continue;
        #pragma unroll
        for (int j = 0; j < 4; ++j) {
            int n = bn + tx * 4 + j;
            float v = acc[i][j];
            if (BIAS) v += bias[n];
            out[(size_t)m * N + n] = v;
        }
    }
}

// ---------------- CSR gather-aggregate ----------------
// out[i] = dinv[i]*(sum_e dinv[s]*in[s] + dinv[i]*in[i]) [+bias] [relu]
// NPB nodes per 256-thread block; local node = tid/D is wave-aligned, so the
// edge loop is wave-uniform -> readfirstlane legal, scalar loads for colidx/dinv.

template<int D, int NPB, bool BIAS, bool RELU>
__global__ __launch_bounds__(256) void agg_kernel(const float* __restrict__ in,
        const float* __restrict__ bias,
        const int* __restrict__ rowptr, const int* __restrict__ colidx,
        const float* __restrict__ dinv, float* __restrict__ out, int n) {
    const int local = (int)threadIdx.x / D;
    const int d     = (int)threadIdx.x % D;
    const int i = blockIdx.x * NPB + local;
    if (i >= n) return;
    const float di = dinv[i];
    float acc = di * in[(size_t)i * D + d];           // self-loop term
    int e = rowptr[i];
    const int e1 = rowptr[i + 1];
    // 4-way unroll: 4 independent row-gathers in flight per iteration
    for (; e + 4 <= e1; e += 4) {
        int s0 = __builtin_amdgcn_readfirstlane(colidx[e + 0]);
        int s1 = __builtin_amdgcn_readfirstlane(colidx[e + 1]);
        int s2 = __builtin_amdgcn_readfirstlane(colidx[e + 2]);
        int s3 = __builtin_amdgcn_readfirstlane(colidx[e + 3]);
        float w0 = dinv[s0], w1 = dinv[s1], w2 = dinv[s2], w3 = dinv[s3];
        float v0 = in[(size_t)s0 * D + d];
        float v1 = in[(size_t)s1 * D + d];
        float v2 = in[(size_t)s2 * D + d];
        float v3 = in[(size_t)s3 * D + d];
        acc += w0 * v0;
        acc += w1 * v1;
        acc += w2 * v2;
        acc += w3 * v3;
    }
    for (; e < e1; ++e) {
        int s = __builtin_amdgcn_readfirstlane(colidx[e]);
        acc += dinv[s] * in[(size_t)s * D + d];
    }
    float v = di * acc;
    if (BIAS) v += bias[d];
    if (RELU) v = fmaxf(v, 0.0f);
    out[(size_t)i * D + d] = v;
}

// ---------------- driver ----------------

extern "C" void kernel_launch(void* const* d_in, const int* in_sizes, int n_in,
                              void* d_out, int out_size, void* d_ws, size_t ws_size,
                              hipStream_t stream) {
    const float* x  = (const float*)d_in[0];
    const int*   ei = (const int*)d_in[1];
    const float* W1 = (const float*)d_in[2];
    const float* b1 = (const float*)d_in[3];
    const float* W2 = (const float*)d_in[4];
    const float* b2 = (const float*)d_in[5];
    const float* W3 = (const float*)d_in[6];
    const float* b3 = (const float*)d_in[7];

    const int IN = 128;
    const int n  = in_sizes[0] / IN;   // 50000
    const int E  = in_sizes[1] / 2;    // 800000

    char* ws = (char*)d_ws;
    size_t off = 0;
    auto alloc = [&](size_t bytes) {
        char* p = ws + off;
        off += (bytes + 255) & ~(size_t)255;
        return p;
    };
    float* bufA   = (float*)alloc((size_t)n * 128 * sizeof(float));  // 25.6 MB
    float* bufB   = (float*)alloc((size_t)n * 128 * sizeof(float));  // 25.6 MB
    float* bufC   = (float*)alloc((size_t)n * 64  * sizeof(float));  // 12.8 MB
    int*   deg    = (int*)  alloc((size_t)n * sizeof(int));
    int*   rowptr = (int*)  alloc(((size_t)n + 1) * sizeof(int));
    int*   cursor = (int*)  alloc((size_t)n * sizeof(int));
    float* dinv   = (float*)alloc((size_t)n * sizeof(float));
    int*   colidx = (int*)  alloc((size_t)E * sizeof(int));          // 3.2 MB

    // ---- CSR build (once per call, shared by all 3 layers) ----
    hipMemsetAsync(deg,    0, (size_t)n * sizeof(int), stream);
    hipMemsetAsync(cursor, 0, (size_t)n * sizeof(int), stream);
    count_kernel<<<ceil_div(E, 256), 256, 0, stream>>>(ei, deg, E);
    scan_kernel<<<1, 1024, 0, stream>>>(deg, rowptr, dinv, n);
    fill_kernel<<<ceil_div(E, 256), 256, 0, stream>>>(ei, rowptr, cursor, colidx, E);

    // ---- Layer 1: h1 = relu(Agg(x @ W1) + b1)  (agg at 128) ----
    dim3 g1(ceil_div(n, 64), 2);
    gemm_kernel<128, 128, false><<<g1, 256, 0, stream>>>(x, W1, nullptr, bufA, n);
    agg_kernel<128, 2, true, true><<<ceil_div(n, 2), 256, 0, stream>>>(
        bufA, b1, rowptr, colidx, dinv, bufB, n);

    // ---- Layer 2: h2 = relu(Agg(h1 @ W2) + b2)  (transform first -> agg at 64) ----
    dim3 g2(ceil_div(n, 64), 1);
    gemm_kernel<128, 64, false><<<g2, 256, 0, stream>>>(bufB, W2, nullptr, bufC, n);
    agg_kernel<64, 4, true, true><<<ceil_div(n, 4), 256, 0, stream>>>(
        bufC, b2, rowptr, colidx, dinv, bufA, n);

    // ---- Layer 3: out = Agg(h2) @ W3 + b3  (agg first at 64; Agg commutes with W) ----
    agg_kernel<64, 4, false, false><<<ceil_div(n, 4), 256, 0, stream>>>(
        bufA, nullptr, rowptr, colidx, dinv, bufC, n);
    dim3 g3(ceil_div(n, 64), 2);
    gemm_kernel<64, 128, true><<<g3, 256, 0, stream>>>(bufC, W3, b3, (float*)d_out, n);
}

// Round 3
// 373.186 us; speedup vs baseline: 1.2602x; 1.2602x over previous
//
#include <hip/hip_runtime.h>

static inline int ceil_div(int a, int b) { return (a + b - 1) / b; }

// ---------------- CSR build ----------------

__global__ void count_kernel(const int* __restrict__ ei, int* __restrict__ deg, int E) {
    int e = blockIdx.x * blockDim.x + threadIdx.x;
    if (e < E) atomicAdd(&deg[ei[E + e]], 1);   // row 1 of edge_index = dst
}

// ---- 3-phase grid prefix scan of deg -> rowptr (exclusive), plus dinv ----
// Tile = 1024 elems per 256-thread block (4/thread). nb = ceil(n/1024) <= 64.

__global__ __launch_bounds__(256) void block_sum_kernel(const int* __restrict__ deg,
        int* __restrict__ bsum, int n) {
    int base = blockIdx.x * 1024 + (int)threadIdx.x * 4;
    int s = 0;
    #pragma unroll
    for (int j = 0; j < 4; ++j) { int i = base + j; if (i < n) s += deg[i]; }
    #pragma unroll
    for (int off = 32; off > 0; off >>= 1) s += __shfl_down(s, off);
    __shared__ int ws[4];
    int wid = (int)threadIdx.x >> 6, lane = (int)threadIdx.x & 63;
    if (lane == 0) ws[wid] = s;
    __syncthreads();
    if (threadIdx.x == 0) bsum[blockIdx.x] = ws[0] + ws[1] + ws[2] + ws[3];
}

// single wave scans nb (<=64) block sums; boff[b] = exclusive offset; rowptr[n] = total
__global__ void scan_bsum_kernel(const int* __restrict__ bsum, int* __restrict__ boff,
        int* __restrict__ rowptr, int nb, int n) {
    int tid = (int)threadIdx.x;
    int v = (tid < nb) ? bsum[tid] : 0;
    #pragma unroll
    for (int off = 1; off < 64; off <<= 1) {
        int u = __shfl_up(v, off);
        if (tid >= off) v += u;
    }
    if (tid < nb) boff[tid + 1] = v;
    if (tid == 0) boff[0] = 0;
    if (tid == nb - 1) rowptr[n] = v;
}

__global__ __launch_bounds__(256) void scan_apply_kernel(const int* __restrict__ deg,
        const int* __restrict__ boff, int* __restrict__ rowptr,
        float* __restrict__ dinv, int n) {
    int tid = (int)threadIdx.x;
    int base = blockIdx.x * 1024 + tid * 4;
    int d[4];
    #pragma unroll
    for (int j = 0; j < 4; ++j) { int i = base + j; d[j] = (i < n) ? deg[i] : 0; }
    int tsum = d[0] + d[1] + d[2] + d[3];
    int v = tsum;
    int lane = tid & 63, wid = tid >> 6;
    #pragma unroll
    for (int off = 1; off < 64; off <<= 1) {
        int u = __shfl_up(v, off);
        if (lane >= off) v += u;
    }
    __shared__ int wsum[4];
    if (lane == 63) wsum[wid] = v;
    __syncthreads();
    int wbase = 0;
    #pragma unroll
    for (int w = 0; w < 4; ++w) if (w < wid) wbase += wsum[w];
    int run = boff[blockIdx.x] + wbase + (v - tsum);   // exclusive prefix for this thread
    #pragma unroll
    for (int j = 0; j < 4; ++j) {
        int i = base + j;
        if (i < n) {
            rowptr[i] = run;
            dinv[i] = rsqrtf((float)(d[j] + 1));   // +1 self-loop
        }
        run += d[j];
    }
}

__global__ void fill_kernel(const int* __restrict__ ei, const int* __restrict__ rowptr,
        int* __restrict__ cursor, int* __restrict__ colidx, int E) {
    int e = blockIdx.x * blockDim.x + threadIdx.x;
    if (e < E) {
        int s = ei[e];
        int d = ei[E + e];
        int pos = rowptr[d] + atomicAdd(&cursor[d], 1);
        colidx[pos] = s;
    }
}

// ---------------- fp32 tiled GEMM: out[M,N] = A[M,K] @ W[K,N] (+bias) ----------------

template<int K, int N, bool BIAS>
__global__ __launch_bounds__(256) void gemm_kernel(const float* __restrict__ A,
        const float* __restrict__ W, const float* __restrict__ bias,
        float* __restrict__ out, int M) {
    __shared__ float As[16][68];   // [k][m], padded
    __shared__ float Bs[16][68];   // [k][n]
    const int bm = blockIdx.x * 64;
    const int bn = blockIdx.y * 64;
    const int tid = (int)threadIdx.x;
    const int tx = tid & 15;
    const int ty = tid >> 4;
    float acc[4][4] = {};
    for (int k0 = 0; k0 < K; k0 += 16) {
        {   // A tile: 64 rows x 16 k, float4-coalesced, stored transposed
            int m   = tid >> 2;
            int kk4 = (tid & 3) * 4;
            float4 v = make_float4(0.f, 0.f, 0.f, 0.f);
            if (bm + m < M)
                v = *(const float4*)&A[(size_t)(bm + m) * K + k0 + kk4];
            As[kk4 + 0][m] = v.x;
            As[kk4 + 1][m] = v.y;
            As[kk4 + 2][m] = v.z;
            As[kk4 + 3][m] = v.w;
        }
        {   // B tile: 16 k x 64 n
            int kk = tid >> 4;
            int n4 = (tid & 15) * 4;
            *(float4*)&Bs[kk][n4] = *(const float4*)&W[(size_t)(k0 + kk) * N + bn + n4];
        }
        __syncthreads();
        #pragma unroll
        for (int kk = 0; kk < 16; ++kk) {
            float4 a4 = *(const float4*)&As[kk][ty * 4];
            float4 b4 = *(const float4*)&Bs[kk][tx * 4];
            float a[4] = {a4.x, a4.y, a4.z, a4.w};
            float b[4] = {b4.x, b4.y, b4.z, b4.w};
            #pragma unroll
            for (int i = 0; i < 4; ++i)
                #pragma unroll
                for (int j = 0; j < 4; ++j)
                    acc[i][j] += a[i] * b[j];
        }
        __syncthreads();
    }
    #pragma unroll
    for (int i = 0; i < 4; ++i) {
        int m = bm + ty * 4 + i;
        if (m >= M) continue;
        #pragma unroll
        for (int j = 0; j < 4; ++j) {
            int n = bn + tx * 4 + j;
            float v = acc[i][j];
            if (BIAS) v += bias[n];
            out[(size_t)m * N + n] = v;
        }
    }
}

// ---------------- CSR gather-aggregate ----------------
// out[i] = dinv[i]*(sum_e dinv[s]*in[s] + dinv[i]*in[i]) [+bias] [relu]
// NPB nodes per 256-thread block; local node = tid/D is wave-aligned, so the
// edge loop is wave-uniform -> readfirstlane legal, scalar loads for colidx/dinv.

template<int D, int NPB, bool BIAS, bool RELU>
__global__ __launch_bounds__(256) void agg_kernel(const float* __restrict__ in,
        const float* __restrict__ bias,
        const int* __restrict__ rowptr, const int* __restrict__ colidx,
        const float* __restrict__ dinv, float* __restrict__ out, int n) {
    const int local = (int)threadIdx.x / D;
    const int d     = (int)threadIdx.x % D;
    const int i = blockIdx.x * NPB + local;
    if (i >= n) return;
    const float di = dinv[i];
    float acc = di * in[(size_t)i * D + d];           // self-loop term
    int e = rowptr[i];
    const int e1 = rowptr[i + 1];
    // 4-way unroll: 4 independent row-gathers in flight per iteration
    for (; e + 4 <= e1; e += 4) {
        int s0 = __builtin_amdgcn_readfirstlane(colidx[e + 0]);
        int s1 = __builtin_amdgcn_readfirstlane(colidx[e + 1]);
        int s2 = __builtin_amdgcn_readfirstlane(colidx[e + 2]);
        int s3 = __builtin_amdgcn_readfirstlane(colidx[e + 3]);
        float w0 = dinv[s0], w1 = dinv[s1], w2 = dinv[s2], w3 = dinv[s3];
        float v0 = in[(size_t)s0 * D + d];
        float v1 = in[(size_t)s1 * D + d];
        float v2 = in[(size_t)s2 * D + d];
        float v3 = in[(size_t)s3 * D + d];
        acc += w0 * v0;
        acc += w1 * v1;
        acc += w2 * v2;
        acc += w3 * v3;
    }
    for (; e < e1; ++e) {
        int s = __builtin_amdgcn_readfirstlane(colidx[e]);
        acc += dinv[s] * in[(size_t)s * D + d];
    }
    float v = di * acc;
    if (BIAS) v += bias[d];
    if (RELU) v = fmaxf(v, 0.0f);
    out[(size_t)i * D + d] = v;
}

// ---------------- driver ----------------

extern "C" void kernel_launch(void* const* d_in, const int* in_sizes, int n_in,
                              void* d_out, int out_size, void* d_ws, size_t ws_size,
                              hipStream_t stream) {
    const float* x  = (const float*)d_in[0];
    const int*   ei = (const int*)d_in[1];
    const float* W1 = (const float*)d_in[2];
    const float* b1 = (const float*)d_in[3];
    const float* W2 = (const float*)d_in[4];
    const float* b2 = (const float*)d_in[5];
    const float* W3 = (const float*)d_in[6];
    const float* b3 = (const float*)d_in[7];

    const int IN = 128;
    const int n  = in_sizes[0] / IN;   // 50000
    const int E  = in_sizes[1] / 2;    // 800000

    char* ws = (char*)d_ws;
    size_t off = 0;
    auto alloc = [&](size_t bytes) {
        char* p = ws + off;
        off += (bytes + 255) & ~(size_t)255;
        return p;
    };
    float* bufA   = (float*)alloc((size_t)n * 128 * sizeof(float));  // 25.6 MB
    float* bufB   = (float*)alloc((size_t)n * 128 * sizeof(float));  // 25.6 MB
    float* bufC   = (float*)alloc((size_t)n * 64  * sizeof(float));  // 12.8 MB
    int*   deg    = (int*)  alloc((size_t)n * sizeof(int));
    int*   rowptr = (int*)  alloc(((size_t)n + 1) * sizeof(int));
    int*   cursor = (int*)  alloc((size_t)n * sizeof(int));
    float* dinv   = (float*)alloc((size_t)n * sizeof(float));
    int*   colidx = (int*)  alloc((size_t)E * sizeof(int));          // 3.2 MB
    int*   bsum   = (int*)  alloc(64 * sizeof(int));
    int*   boff   = (int*)  alloc(65 * sizeof(int));

    const int nb = ceil_div(n, 1024);   // 49 <= 64

    // ---- CSR build (once per call, shared by all 3 layers) ----
    hipMemsetAsync(deg,    0, (size_t)n * sizeof(int), stream);
    hipMemsetAsync(cursor, 0, (size_t)n * sizeof(int), stream);
    count_kernel<<<ceil_div(E, 256), 256, 0, stream>>>(ei, deg, E);
    block_sum_kernel<<<nb, 256, 0, stream>>>(deg, bsum, n);
    scan_bsum_kernel<<<1, 64, 0, stream>>>(bsum, boff, rowptr, nb, n);
    scan_apply_kernel<<<nb, 256, 0, stream>>>(deg, boff, rowptr, dinv, n);
    fill_kernel<<<ceil_div(E, 256), 256, 0, stream>>>(ei, rowptr, cursor, colidx, E);

    // ---- Layer 1: h1 = relu(Agg(x @ W1) + b1)  (agg at 128) ----
    dim3 g1(ceil_div(n, 64), 2);
    gemm_kernel<128, 128, false><<<g1, 256, 0, stream>>>(x, W1, nullptr, bufA, n);
    agg_kernel<128, 2, true, true><<<ceil_div(n, 2), 256, 0, stream>>>(
        bufA, b1, rowptr, colidx, dinv, bufB, n);

    // ---- Layer 2: h2 = relu(Agg(h1 @ W2) + b2)  (transform first -> agg at 64) ----
    dim3 g2(ceil_div(n, 64), 1);
    gemm_kernel<128, 64, false><<<g2, 256, 0, stream>>>(bufB, W2, nullptr, bufC, n);
    agg_kernel<64, 4, true, true><<<ceil_div(n, 4), 256, 0, stream>>>(
        bufC, b2, rowptr, colidx, dinv, bufA, n);

    // ---- Layer 3: out = Agg(h2) @ W3 + b3  (agg first at 64; Agg commutes with W) ----
    agg_kernel<64, 4, false, false><<<ceil_div(n, 4), 256, 0, stream>>>(
        bufA, nullptr, rowptr, colidx, dinv, bufC, n);
    dim3 g3(ceil_div(n, 64), 2);
    gemm_kernel<64, 128, true><<<g3, 256, 0, stream>>>(bufC, W3, b3, (float*)d_out, n);
}

// Round 4
// 342.218 us; speedup vs baseline: 1.3743x; 1.0905x over previous
//
#include <hip/hip_runtime.h>
#include <hip/hip_bf16.h>

static inline int ceil_div(int a, int b) { return (a + b - 1) / b; }

// ---------------- CSR build ----------------

__global__ void count_kernel(const int* __restrict__ ei, int* __restrict__ deg, int E) {
    int e = blockIdx.x * blockDim.x + threadIdx.x;
    if (e < E) atomicAdd(&deg[ei[E + e]], 1);   // row 1 of edge_index = dst
}

// ---- 3-phase grid prefix scan of deg -> rowptr (exclusive), plus dinv ----

__global__ __launch_bounds__(256) void block_sum_kernel(const int* __restrict__ deg,
        int* __restrict__ bsum, int n) {
    int base = blockIdx.x * 1024 + (int)threadIdx.x * 4;
    int s = 0;
    #pragma unroll
    for (int j = 0; j < 4; ++j) { int i = base + j; if (i < n) s += deg[i]; }
    #pragma unroll
    for (int off = 32; off > 0; off >>= 1) s += __shfl_down(s, off);
    __shared__ int ws[4];
    int wid = (int)threadIdx.x >> 6, lane = (int)threadIdx.x & 63;
    if (lane == 0) ws[wid] = s;
    __syncthreads();
    if (threadIdx.x == 0) bsum[blockIdx.x] = ws[0] + ws[1] + ws[2] + ws[3];
}

__global__ void scan_bsum_kernel(const int* __restrict__ bsum, int* __restrict__ boff,
        int* __restrict__ rowptr, int nb, int n) {
    int tid = (int)threadIdx.x;
    int v = (tid < nb) ? bsum[tid] : 0;
    #pragma unroll
    for (int off = 1; off < 64; off <<= 1) {
        int u = __shfl_up(v, off);
        if (tid >= off) v += u;
    }
    if (tid < nb) boff[tid + 1] = v;
    if (tid == 0) boff[0] = 0;
    if (tid == nb - 1) rowptr[n] = v;
}

__global__ __launch_bounds__(256) void scan_apply_kernel(const int* __restrict__ deg,
        const int* __restrict__ boff, int* __restrict__ rowptr,
        float* __restrict__ dinv, int n) {
    int tid = (int)threadIdx.x;
    int base = blockIdx.x * 1024 + tid * 4;
    int d[4];
    #pragma unroll
    for (int j = 0; j < 4; ++j) { int i = base + j; d[j] = (i < n) ? deg[i] : 0; }
    int tsum = d[0] + d[1] + d[2] + d[3];
    int v = tsum;
    int lane = tid & 63, wid = tid >> 6;
    #pragma unroll
    for (int off = 1; off < 64; off <<= 1) {
        int u = __shfl_up(v, off);
        if (lane >= off) v += u;
    }
    __shared__ int wsum[4];
    if (lane == 63) wsum[wid] = v;
    __syncthreads();
    int wbase = 0;
    #pragma unroll
    for (int w = 0; w < 4; ++w) if (w < wid) wbase += wsum[w];
    int run = boff[blockIdx.x] + wbase + (v - tsum);
    #pragma unroll
    for (int j = 0; j < 4; ++j) {
        int i = base + j;
        if (i < n) {
            rowptr[i] = run;
            dinv[i] = rsqrtf((float)(d[j] + 1));   // +1 self-loop
        }
        run += d[j];
    }
}

__global__ void fill_kernel(const int* __restrict__ ei, const int* __restrict__ rowptr,
        int* __restrict__ cursor, int* __restrict__ colidx, int E) {
    int e = blockIdx.x * blockDim.x + threadIdx.x;
    if (e < E) {
        int s = ei[e];
        int d = ei[E + e];
        int pos = rowptr[d] + atomicAdd(&cursor[d], 1);
        colidx[pos] = s;
    }
}

// ---------------- fp32 tiled GEMM: out[M,N] = A[M,K] @ W[K,N] (+bias), fp32 or bf16 out ----

template<int K, int N, bool BIAS, bool OUT_BF16>
__global__ __launch_bounds__(256) void gemm_kernel(const float* __restrict__ A,
        const float* __restrict__ W, const float* __restrict__ bias,
        void* __restrict__ out_, int M) {
    __shared__ float As[16][68];   // [k][m], padded
    __shared__ float Bs[16][68];   // [k][n]
    const int bm = blockIdx.x * 64;
    const int bn = blockIdx.y * 64;
    const int tid = (int)threadIdx.x;
    const int tx = tid & 15;
    const int ty = tid >> 4;
    float acc[4][4] = {};
    for (int k0 = 0; k0 < K; k0 += 16) {
        {   // A tile: 64 rows x 16 k, float4-coalesced, stored transposed
            int m   = tid >> 2;
            int kk4 = (tid & 3) * 4;
            float4 v = make_float4(0.f, 0.f, 0.f, 0.f);
            if (bm + m < M)
                v = *(const float4*)&A[(size_t)(bm + m) * K + k0 + kk4];
            As[kk4 + 0][m] = v.x;
            As[kk4 + 1][m] = v.y;
            As[kk4 + 2][m] = v.z;
            As[kk4 + 3][m] = v.w;
        }
        {   // B tile: 16 k x 64 n
            int kk = tid >> 4;
            int n4 = (tid & 15) * 4;
            *(float4*)&Bs[kk][n4] = *(const float4*)&W[(size_t)(k0 + kk) * N + bn + n4];
        }
        __syncthreads();
        #pragma unroll
        for (int kk = 0; kk < 16; ++kk) {
            float4 a4 = *(const float4*)&As[kk][ty * 4];
            float4 b4 = *(const float4*)&Bs[kk][tx * 4];
            float a[4] = {a4.x, a4.y, a4.z, a4.w};
            float b[4] = {b4.x, b4.y, b4.z, b4.w};
            #pragma unroll
            for (int i = 0; i < 4; ++i)
                #pragma unroll
                for (int j = 0; j < 4; ++j)
                    acc[i][j] += a[i] * b[j];
        }
        __syncthreads();
    }
    #pragma unroll
    for (int i = 0; i < 4; ++i) {
        int m = bm + ty * 4 + i;
        if (m >= M) continue;
        float v[4];
        #pragma unroll
        for (int j = 0; j < 4; ++j) {
            v[j] = acc[i][j];
            if (BIAS) v[j] += bias[bn + tx * 4 + j];
        }
        size_t base = (size_t)m * N + bn + tx * 4;
        if constexpr (OUT_BF16) {
            __hip_bfloat16* ob = (__hip_bfloat16*)out_;
            __hip_bfloat162 p0, p1;
            p0.x = __float2bfloat16(v[0]); p0.y = __float2bfloat16(v[1]);
            p1.x = __float2bfloat16(v[2]); p1.y = __float2bfloat16(v[3]);
            *(__hip_bfloat162*)&ob[base]     = p0;
            *(__hip_bfloat162*)&ob[base + 2] = p1;
        } else {
            float* of = (float*)out_;
            *(float2*)&of[base]     = make_float2(v[0], v[1]);
            *(float2*)&of[base + 2] = make_float2(v[2], v[3]);
        }
    }
}

// ---------------- CSR gather-aggregate, bf16 gather operand ----------------
// out[i] = dinv[i]*(sum_e dinv[s]*in_bf16[s] + dinv[i]*in_bf16[i]) [+bias] [relu]
// One wave per node (64 lanes); D=128 -> bf16x2 per lane, D=64 -> bf16 per lane.
// Edge loop is wave-uniform -> readfirstlane legal; 8-deep unroll for MLP.

template<int D, bool BIAS, bool RELU, bool OUT_BF16>
__global__ __launch_bounds__(256) void agg_kernel(const void* __restrict__ in_,
        const float* __restrict__ bias,
        const int* __restrict__ rowptr, const int* __restrict__ colidx,
        const float* __restrict__ dinv, void* __restrict__ out_, int n) {
    constexpr int VPL = D / 64;   // values per lane: 2 (D=128) or 1 (D=64)
    const int lane = (int)threadIdx.x & 63;
    const int wid  = (int)threadIdx.x >> 6;
    const int i = blockIdx.x * 4 + wid;
    if (i >= n) return;
    const float di = dinv[i];
    float acc0 = 0.f, acc1 = 0.f;
    if constexpr (VPL == 2) {
        const __hip_bfloat162* in = (const __hip_bfloat162*)in_;
        __hip_bfloat162 sv = in[(size_t)i * 64 + lane];
        acc0 = di * __bfloat162float(sv.x);
        acc1 = di * __bfloat162float(sv.y);
    } else {
        const __hip_bfloat16* in = (const __hip_bfloat16*)in_;
        acc0 = di * __bfloat162float(in[(size_t)i * 64 + lane]);
    }
    int e = rowptr[i];
    const int e1 = rowptr[i + 1];
    for (; e + 8 <= e1; e += 8) {
        int s[8]; float w[8];
        #pragma unroll
        for (int j = 0; j < 8; ++j) s[j] = __builtin_amdgcn_readfirstlane(colidx[e + j]);
        #pragma unroll
        for (int j = 0; j < 8; ++j) w[j] = dinv[s[j]];
        if constexpr (VPL == 2) {
            const __hip_bfloat162* in = (const __hip_bfloat162*)in_;
            __hip_bfloat162 v[8];
            #pragma unroll
            for (int j = 0; j < 8; ++j) v[j] = in[(size_t)s[j] * 64 + lane];
            #pragma unroll
            for (int j = 0; j < 8; ++j) {
                acc0 += w[j] * __bfloat162float(v[j].x);
                acc1 += w[j] * __bfloat162float(v[j].y);
            }
        } else {
            const __hip_bfloat16* in = (const __hip_bfloat16*)in_;
            __hip_bfloat16 v[8];
            #pragma unroll
            for (int j = 0; j < 8; ++j) v[j] = in[(size_t)s[j] * 64 + lane];
            #pragma unroll
            for (int j = 0; j < 8; ++j) acc0 += w[j] * __bfloat162float(v[j]);
        }
    }
    for (; e < e1; ++e) {
        int s = __builtin_amdgcn_readfirstlane(colidx[e]);
        float w = dinv[s];
        if constexpr (VPL == 2) {
            const __hip_bfloat162* in = (const __hip_bfloat162*)in_;
            __hip_bfloat162 v = in[(size_t)s * 64 + lane];
            acc0 += w * __bfloat162float(v.x);
            acc1 += w * __bfloat162float(v.y);
        } else {
            const __hip_bfloat16* in = (const __hip_bfloat16*)in_;
            acc0 += w * __bfloat162float(in[(size_t)s * 64 + lane]);
        }
    }
    float v0 = di * acc0;
    float v1 = di * acc1;
    if constexpr (VPL == 2) {
        if (BIAS) { v0 += bias[2 * lane]; v1 += bias[2 * lane + 1]; }
        if (RELU) { v0 = fmaxf(v0, 0.f); v1 = fmaxf(v1, 0.f); }
        if constexpr (OUT_BF16) {
            __hip_bfloat162* ob = (__hip_bfloat162*)out_;
            __hip_bfloat162 p; p.x = __float2bfloat16(v0); p.y = __float2bfloat16(v1);
            ob[(size_t)i * 64 + lane] = p;
        } else {
            float2* of = (float2*)out_;
            of[(size_t)i * 64 + lane] = make_float2(v0, v1);
        }
    } else {
        if (BIAS) v0 += bias[lane];
        if (RELU) v0 = fmaxf(v0, 0.f);
        if constexpr (OUT_BF16) {
            __hip_bfloat16* ob = (__hip_bfloat16*)out_;
            ob[(size_t)i * 64 + lane] = __float2bfloat16(v0);
        } else {
            float* of = (float*)out_;
            of[(size_t)i * 64 + lane] = v0;
        }
    }
}

// ---------------- driver ----------------

extern "C" void kernel_launch(void* const* d_in, const int* in_sizes, int n_in,
                              void* d_out, int out_size, void* d_ws, size_t ws_size,
                              hipStream_t stream) {
    const float* x  = (const float*)d_in[0];
    const int*   ei = (const int*)d_in[1];
    const float* W1 = (const float*)d_in[2];
    const float* b1 = (const float*)d_in[3];
    const float* W2 = (const float*)d_in[4];
    const float* b2 = (const float*)d_in[5];
    const float* W3 = (const float*)d_in[6];
    const float* b3 = (const float*)d_in[7];

    const int IN = 128;
    const int n  = in_sizes[0] / IN;   // 50000
    const int E  = in_sizes[1] / 2;    // 800000

    char* ws = (char*)d_ws;
    size_t off = 0;
    auto alloc = [&](size_t bytes) {
        char* p = ws + off;
        off += (bytes + 255) & ~(size_t)255;
        return p;
    };
    __hip_bfloat16* hA_bf = (__hip_bfloat16*)alloc((size_t)n * 128 * 2);  // 12.8 MB (h1 pre-agg)
    float*          bufB  = (float*)alloc((size_t)n * 128 * 4);           // 25.6 MB (h1 post-agg)
    __hip_bfloat16* hC_bf = (__hip_bfloat16*)alloc((size_t)n * 64 * 2);   //  6.4 MB (h1@W2)
    __hip_bfloat16* hD_bf = (__hip_bfloat16*)alloc((size_t)n * 64 * 2);   //  6.4 MB (h2)
    float*          bufE  = (float*)alloc((size_t)n * 64 * 4);            // 12.8 MB (Agg(h2))
    int*   deg    = (int*)  alloc((size_t)n * sizeof(int));
    int*   rowptr = (int*)  alloc(((size_t)n + 1) * sizeof(int));
    int*   cursor = (int*)  alloc((size_t)n * sizeof(int));
    float* dinv   = (float*)alloc((size_t)n * sizeof(float));
    int*   colidx = (int*)  alloc((size_t)E * sizeof(int));               //  3.2 MB
    int*   bsum   = (int*)  alloc(64 * sizeof(int));
    int*   boff   = (int*)  alloc(65 * sizeof(int));

    const int nb = ceil_div(n, 1024);   // 49 <= 64

    // ---- CSR build (once per call, shared by all 3 layers) ----
    hipMemsetAsync(deg,    0, (size_t)n * sizeof(int), stream);
    hipMemsetAsync(cursor, 0, (size_t)n * sizeof(int), stream);
    count_kernel<<<ceil_div(E, 256), 256, 0, stream>>>(ei, deg, E);
    block_sum_kernel<<<nb, 256, 0, stream>>>(deg, bsum, n);
    scan_bsum_kernel<<<1, 64, 0, stream>>>(bsum, boff, rowptr, nb, n);
    scan_apply_kernel<<<nb, 256, 0, stream>>>(deg, boff, rowptr, dinv, n);
    fill_kernel<<<ceil_div(E, 256), 256, 0, stream>>>(ei, rowptr, cursor, colidx, E);

    // ---- Layer 1: h1 = relu(Agg(x @ W1) + b1)  (agg at 128, bf16 gather) ----
    dim3 g1(ceil_div(n, 64), 2);
    gemm_kernel<128, 128, false, true><<<g1, 256, 0, stream>>>(x, W1, nullptr, hA_bf, n);
    agg_kernel<128, true, true, false><<<ceil_div(n, 4), 256, 0, stream>>>(
        hA_bf, b1, rowptr, colidx, dinv, bufB, n);

    // ---- Layer 2: h2 = relu(Agg(h1 @ W2) + b2)  (transform first -> agg at 64, bf16) ----
    dim3 g2(ceil_div(n, 64), 1);
    gemm_kernel<128, 64, false, true><<<g2, 256, 0, stream>>>(bufB, W2, nullptr, hC_bf, n);
    agg_kernel<64, true, true, true><<<ceil_div(n, 4), 256, 0, stream>>>(
        hC_bf, b2, rowptr, colidx, dinv, hD_bf, n);

    // ---- Layer 3: out = Agg(h2) @ W3 + b3  (agg first at 64, bf16; Agg commutes with W) ----
    agg_kernel<64, false, false, false><<<ceil_div(n, 4), 256, 0, stream>>>(
        hD_bf, nullptr, rowptr, colidx, dinv, bufE, n);
    dim3 g3(ceil_div(n, 64), 2);
    gemm_kernel<64, 128, true, false><<<g3, 256, 0, stream>>>(bufE, W3, b3, d_out, n);
}

// Round 5
// 305.771 us; speedup vs baseline: 1.5381x; 1.1192x over previous
//
#include <hip/hip_runtime.h>
#include <hip/hip_bf16.h>

static inline int ceil_div(int a, int b) { return (a + b - 1) / b; }

// ---------------- CSR build ----------------

// Count degrees AND record each edge's rank within its dst segment.
// The atomicAdd return value gives a free unique slot -> fill needs no atomics.
__global__ void count_kernel(const int* __restrict__ ei, int* __restrict__ deg,
        int* __restrict__ rank, int E) {
    int e = blockIdx.x * blockDim.x + threadIdx.x;
    if (e < E) rank[e] = atomicAdd(&deg[ei[E + e]], 1);   // row 1 = dst
}

// ---- 3-phase grid prefix scan of deg -> rowptr (exclusive), plus dinv ----

__global__ __launch_bounds__(256) void block_sum_kernel(const int* __restrict__ deg,
        int* __restrict__ bsum, int n) {
    int base = blockIdx.x * 1024 + (int)threadIdx.x * 4;
    int s = 0;
    #pragma unroll
    for (int j = 0; j < 4; ++j) { int i = base + j; if (i < n) s += deg[i]; }
    #pragma unroll
    for (int off = 32; off > 0; off >>= 1) s += __shfl_down(s, off);
    __shared__ int ws[4];
    int wid = (int)threadIdx.x >> 6, lane = (int)threadIdx.x & 63;
    if (lane == 0) ws[wid] = s;
    __syncthreads();
    if (threadIdx.x == 0) bsum[blockIdx.x] = ws[0] + ws[1] + ws[2] + ws[3];
}

__global__ void scan_bsum_kernel(const int* __restrict__ bsum, int* __restrict__ boff,
        int* __restrict__ rowptr, int nb, int n) {
    int tid = (int)threadIdx.x;
    int v = (tid < nb) ? bsum[tid] : 0;
    #pragma unroll
    for (int off = 1; off < 64; off <<= 1) {
        int u = __shfl_up(v, off);
        if (tid >= off) v += u;
    }
    if (tid < nb) boff[tid + 1] = v;
    if (tid == 0) boff[0] = 0;
    if (tid == nb - 1) rowptr[n] = v;
}

__global__ __launch_bounds__(256) void scan_apply_kernel(const int* __restrict__ deg,
        const int* __restrict__ boff, int* __restrict__ rowptr,
        float* __restrict__ dinv, int n) {
    int tid = (int)threadIdx.x;
    int base = blockIdx.x * 1024 + tid * 4;
    int d[4];
    #pragma unroll
    for (int j = 0; j < 4; ++j) { int i = base + j; d[j] = (i < n) ? deg[i] : 0; }
    int tsum = d[0] + d[1] + d[2] + d[3];
    int v = tsum;
    int lane = tid & 63, wid = tid >> 6;
    #pragma unroll
    for (int off = 1; off < 64; off <<= 1) {
        int u = __shfl_up(v, off);
        if (lane >= off) v += u;
    }
    __shared__ int wsum[4];
    if (lane == 63) wsum[wid] = v;
    __syncthreads();
    int wbase = 0;
    #pragma unroll
    for (int w = 0; w < 4; ++w) if (w < wid) wbase += wsum[w];
    int run = boff[blockIdx.x] + wbase + (v - tsum);
    #pragma unroll
    for (int j = 0; j < 4; ++j) {
        int i = base + j;
        if (i < n) {
            rowptr[i] = run;
            dinv[i] = rsqrtf((float)(d[j] + 1));   // +1 self-loop
        }
        run += d[j];
    }
}

// Atomic-free fill: pos = rowptr[dst] + rank (rank from count_kernel's atomic).
__global__ void fill_kernel(const int* __restrict__ ei, const int* __restrict__ rowptr,
        const int* __restrict__ rank, int* __restrict__ colidx, int E) {
    int e = blockIdx.x * blockDim.x + threadIdx.x;
    if (e < E) {
        int s = ei[e];
        int d = ei[E + e];
        colidx[rowptr[d] + rank[e]] = s;
    }
}

// ---------------- fp32 tiled GEMM: out[M,N] = A[M,K] @ W[K,N] (+bias), fp32 or bf16 out ----

template<int K, int N, bool BIAS, bool OUT_BF16>
__global__ __launch_bounds__(256) void gemm_kernel(const float* __restrict__ A,
        const float* __restrict__ W, const float* __restrict__ bias,
        void* __restrict__ out_, int M) {
    __shared__ float As[16][68];   // [k][m], padded
    __shared__ float Bs[16][68];   // [k][n]
    const int bm = blockIdx.x * 64;
    const int bn = blockIdx.y * 64;
    const int tid = (int)threadIdx.x;
    const int tx = tid & 15;
    const int ty = tid >> 4;
    float acc[4][4] = {};
    for (int k0 = 0; k0 < K; k0 += 16) {
        {   // A tile: 64 rows x 16 k, float4-coalesced, stored transposed
            int m   = tid >> 2;
            int kk4 = (tid & 3) * 4;
            float4 v = make_float4(0.f, 0.f, 0.f, 0.f);
            if (bm + m < M)
                v = *(const float4*)&A[(size_t)(bm + m) * K + k0 + kk4];
            As[kk4 + 0][m] = v.x;
            As[kk4 + 1][m] = v.y;
            As[kk4 + 2][m] = v.z;
            As[kk4 + 3][m] = v.w;
        }
        {   // B tile: 16 k x 64 n
            int kk = tid >> 4;
            int n4 = (tid & 15) * 4;
            *(float4*)&Bs[kk][n4] = *(const float4*)&W[(size_t)(k0 + kk) * N + bn + n4];
        }
        __syncthreads();
        #pragma unroll
        for (int kk = 0; kk < 16; ++kk) {
            float4 a4 = *(const float4*)&As[kk][ty * 4];
            float4 b4 = *(const float4*)&Bs[kk][tx * 4];
            float a[4] = {a4.x, a4.y, a4.z, a4.w};
            float b[4] = {b4.x, b4.y, b4.z, b4.w};
            #pragma unroll
            for (int i = 0; i < 4; ++i)
                #pragma unroll
                for (int j = 0; j < 4; ++j)
                    acc[i][j] += a[i] * b[j];
        }
        __syncthreads();
    }
    #pragma unroll
    for (int i = 0; i < 4; ++i) {
        int m = bm + ty * 4 + i;
        if (m >= M) continue;
        float v[4];
        #pragma unroll
        for (int j = 0; j < 4; ++j) {
            v[j] = acc[i][j];
            if (BIAS) v[j] += bias[bn + tx * 4 + j];
        }
        size_t base = (size_t)m * N + bn + tx * 4;
        if constexpr (OUT_BF16) {
            __hip_bfloat16* ob = (__hip_bfloat16*)out_;
            __hip_bfloat162 p0, p1;
            p0.x = __float2bfloat16(v[0]); p0.y = __float2bfloat16(v[1]);
            p1.x = __float2bfloat16(v[2]); p1.y = __float2bfloat16(v[3]);
            *(__hip_bfloat162*)&ob[base]     = p0;
            *(__hip_bfloat162*)&ob[base + 2] = p1;
        } else {
            float* of = (float*)out_;
            *(float2*)&of[base]     = make_float2(v[0], v[1]);
            *(float2*)&of[base + 2] = make_float2(v[2], v[3]);
        }
    }
}

// ---------------- CSR gather-aggregate, bf16 gather operand ----------------
// out[i] = dinv[i]*(sum_e dinv[s]*in_bf16[s] + dinv[i]*in_bf16[i]) [+bias] [relu]
// One wave per node (64 lanes); D=128 -> bf16x2 per lane, D=64 -> bf16 per lane.
// Edge loop is wave-uniform -> readfirstlane legal; 8-deep unroll for MLP.

template<int D, bool BIAS, bool RELU, bool OUT_BF16>
__global__ __launch_bounds__(256) void agg_kernel(const void* __restrict__ in_,
        const float* __restrict__ bias,
        const int* __restrict__ rowptr, const int* __restrict__ colidx,
        const float* __restrict__ dinv, void* __restrict__ out_, int n) {
    constexpr int VPL = D / 64;   // values per lane: 2 (D=128) or 1 (D=64)
    const int lane = (int)threadIdx.x & 63;
    const int wid  = (int)threadIdx.x >> 6;
    const int i = blockIdx.x * 4 + wid;
    if (i >= n) return;
    const float di = dinv[i];
    float acc0 = 0.f, acc1 = 0.f;
    if constexpr (VPL == 2) {
        const __hip_bfloat162* in = (const __hip_bfloat162*)in_;
        __hip_bfloat162 sv = in[(size_t)i * 64 + lane];
        acc0 = di * __bfloat162float(sv.x);
        acc1 = di * __bfloat162float(sv.y);
    } else {
        const __hip_bfloat16* in = (const __hip_bfloat16*)in_;
        acc0 = di * __bfloat162float(in[(size_t)i * 64 + lane]);
    }
    int e = rowptr[i];
    const int e1 = rowptr[i + 1];
    for (; e + 8 <= e1; e += 8) {
        int s[8]; float w[8];
        #pragma unroll
        for (int j = 0; j < 8; ++j) s[j] = __builtin_amdgcn_readfirstlane(colidx[e + j]);
        #pragma unroll
        for (int j = 0; j < 8; ++j) w[j] = dinv[s[j]];
        if constexpr (VPL == 2) {
            const __hip_bfloat162* in = (const __hip_bfloat162*)in_;
            __hip_bfloat162 v[8];
            #pragma unroll
            for (int j = 0; j < 8; ++j) v[j] = in[(size_t)s[j] * 64 + lane];
            #pragma unroll
            for (int j = 0; j < 8; ++j) {
                acc0 += w[j] * __bfloat162float(v[j].x);
                acc1 += w[j] * __bfloat162float(v[j].y);
            }
        } else {
            const __hip_bfloat16* in = (const __hip_bfloat16*)in_;
            __hip_bfloat16 v[8];
            #pragma unroll
            for (int j = 0; j < 8; ++j) v[j] = in[(size_t)s[j] * 64 + lane];
            #pragma unroll
            for (int j = 0; j < 8; ++j) acc0 += w[j] * __bfloat162float(v[j]);
        }
    }
    for (; e < e1; ++e) {
        int s = __builtin_amdgcn_readfirstlane(colidx[e]);
        float w = dinv[s];
        if constexpr (VPL == 2) {
            const __hip_bfloat162* in = (const __hip_bfloat162*)in_;
            __hip_bfloat162 v = in[(size_t)s * 64 + lane];
            acc0 += w * __bfloat162float(v.x);
            acc1 += w * __bfloat162float(v.y);
        } else {
            const __hip_bfloat16* in = (const __hip_bfloat16*)in_;
            acc0 += w * __bfloat162float(in[(size_t)s * 64 + lane]);
        }
    }
    float v0 = di * acc0;
    float v1 = di * acc1;
    if constexpr (VPL == 2) {
        if (BIAS) { v0 += bias[2 * lane]; v1 += bias[2 * lane + 1]; }
        if (RELU) { v0 = fmaxf(v0, 0.f); v1 = fmaxf(v1, 0.f); }
        if constexpr (OUT_BF16) {
            __hip_bfloat162* ob = (__hip_bfloat162*)out_;
            __hip_bfloat162 p; p.x = __float2bfloat16(v0); p.y = __float2bfloat16(v1);
            ob[(size_t)i * 64 + lane] = p;
        } else {
            float2* of = (float2*)out_;
            of[(size_t)i * 64 + lane] = make_float2(v0, v1);
        }
    } else {
        if (BIAS) v0 += bias[lane];
        if (RELU) v0 = fmaxf(v0, 0.f);
        if constexpr (OUT_BF16) {
            __hip_bfloat16* ob = (__hip_bfloat16*)out_;
            ob[(size_t)i * 64 + lane] = __float2bfloat16(v0);
        } else {
            float* of = (float*)out_;
            of[(size_t)i * 64 + lane] = v0;
        }
    }
}

// ---------------- driver ----------------

extern "C" void kernel_launch(void* const* d_in, const int* in_sizes, int n_in,
                              void* d_out, int out_size, void* d_ws, size_t ws_size,
                              hipStream_t stream) {
    const float* x  = (const float*)d_in[0];
    const int*   ei = (const int*)d_in[1];
    const float* W1 = (const float*)d_in[2];
    const float* b1 = (const float*)d_in[3];
    const float* W2 = (const float*)d_in[4];
    const float* b2 = (const float*)d_in[5];
    const float* W3 = (const float*)d_in[6];
    const float* b3 = (const float*)d_in[7];

    const int IN = 128;
    const int n  = in_sizes[0] / IN;   // 50000
    const int E  = in_sizes[1] / 2;    // 800000

    char* ws = (char*)d_ws;
    size_t off = 0;
    auto alloc = [&](size_t bytes) {
        char* p = ws + off;
        off += (bytes + 255) & ~(size_t)255;
        return p;
    };
    __hip_bfloat16* hA_bf = (__hip_bfloat16*)alloc((size_t)n * 128 * 2);  // 12.8 MB (h1 pre-agg)
    float*          bufB  = (float*)alloc((size_t)n * 128 * 4);           // 25.6 MB (h1 post-agg)
    __hip_bfloat16* hC_bf = (__hip_bfloat16*)alloc((size_t)n * 64 * 2);   //  6.4 MB (h1@W2)
    __hip_bfloat16* hD_bf = (__hip_bfloat16*)alloc((size_t)n * 64 * 2);   //  6.4 MB (h2)
    float*          bufE  = (float*)alloc((size_t)n * 64 * 4);            // 12.8 MB (Agg(h2))
    int*   deg    = (int*)  alloc((size_t)n * sizeof(int));
    int*   rowptr = (int*)  alloc(((size_t)n + 1) * sizeof(int));
    float* dinv   = (float*)alloc((size_t)n * sizeof(float));
    int*   colidx = (int*)  alloc((size_t)E * sizeof(int));               //  3.2 MB
    int*   rank   = (int*)  alloc((size_t)E * sizeof(int));               //  3.2 MB
    int*   bsum   = (int*)  alloc(64 * sizeof(int));
    int*   boff   = (int*)  alloc(65 * sizeof(int));

    const int nb = ceil_div(n, 1024);   // 49 <= 64

    // ---- CSR build (once per call, shared by all 3 layers) ----
    hipMemsetAsync(deg, 0, (size_t)n * sizeof(int), stream);
    count_kernel<<<ceil_div(E, 256), 256, 0, stream>>>(ei, deg, rank, E);
    block_sum_kernel<<<nb, 256, 0, stream>>>(deg, bsum, n);
    scan_bsum_kernel<<<1, 64, 0, stream>>>(bsum, boff, rowptr, nb, n);
    scan_apply_kernel<<<nb, 256, 0, stream>>>(deg, boff, rowptr, dinv, n);
    fill_kernel<<<ceil_div(E, 256), 256, 0, stream>>>(ei, rowptr, rank, colidx, E);

    // ---- Layer 1: h1 = relu(Agg(x @ W1) + b1)  (agg at 128, bf16 gather) ----
    dim3 g1(ceil_div(n, 64), 2);
    gemm_kernel<128, 128, false, true><<<g1, 256, 0, stream>>>(x, W1, nullptr, hA_bf, n);
    agg_kernel<128, true, true, false><<<ceil_div(n, 4), 256, 0, stream>>>(
        hA_bf, b1, rowptr, colidx, dinv, bufB, n);

    // ---- Layer 2: h2 = relu(Agg(h1 @ W2) + b2)  (transform first -> agg at 64, bf16) ----
    dim3 g2(ceil_div(n, 64), 1);
    gemm_kernel<128, 64, false, true><<<g2, 256, 0, stream>>>(bufB, W2, nullptr, hC_bf, n);
    agg_kernel<64, true, true, true><<<ceil_div(n, 4), 256, 0, stream>>>(
        hC_bf, b2, rowptr, colidx, dinv, hD_bf, n);

    // ---- Layer 3: out = Agg(h2) @ W3 + b3  (agg first at 64, bf16; Agg commutes with W) ----
    agg_kernel<64, false, false, false><<<ceil_div(n, 4), 256, 0, stream>>>(
        hD_bf, nullptr, rowptr, colidx, dinv, bufE, n);
    dim3 g3(ceil_div(n, 64), 2);
    gemm_kernel<64, 128, true, false><<<g3, 256, 0, stream>>>(bufE, W3, b3, d_out, n);
}

// Round 6
// 292.725 us; speedup vs baseline: 1.6066x; 1.0446x over previous
//
#include <hip/hip_runtime.h>
#include <hip/hip_bf16.h>

static inline int ceil_div(int a, int b) { return (a + b - 1) / b; }

// ================= Atomic-free CSR build: 2-level MSD bucket sort =================
// Bucket = dst >> 8 (nbucket = ceil(n/256) <= 512). No global atomics anywhere.

#define CSR_NBLK 64   // blocks for K0/K2 (same chunk mapping in both)

// K0: per-block LDS histogram of coarse buckets
__global__ __launch_bounds__(1024) void bucket_hist_kernel(const int* __restrict__ ei,
        int* __restrict__ hist_b, int E, int nbucket, int chunk) {
    __shared__ int h[512];
    for (int i = threadIdx.x; i < nbucket; i += blockDim.x) h[i] = 0;
    __syncthreads();
    const int b = blockIdx.x;
    const int e0 = b * chunk, e1 = min(E, e0 + chunk);
    for (int e = e0 + (int)threadIdx.x; e < e1; e += blockDim.x)
        atomicAdd(&h[ei[E + e] >> 8], 1);              // LDS atomic
    __syncthreads();
    for (int i = threadIdx.x; i < nbucket; i += blockDim.x)
        hist_b[i * CSR_NBLK + b] = h[i];
}

// K1: single block. Scan bucket totals -> bucket_start; hist_b -> per-block bases (in place).
__global__ __launch_bounds__(512) void bucket_scan_kernel(int* __restrict__ hist_b,
        int* __restrict__ bucket_start, int nbucket, int E) {
    __shared__ int sc[512];
    const int t = (int)threadIdx.x;
    int tot = 0;
    if (t < nbucket) {
        #pragma unroll 8
        for (int b = 0; b < CSR_NBLK; ++b) tot += hist_b[t * CSR_NBLK + b];
    }
    sc[t] = tot;
    __syncthreads();
    for (int off = 1; off < 512; off <<= 1) {          // inclusive Hillis-Steele
        int v = (t >= off) ? sc[t - off] : 0;
        __syncthreads();
        sc[t] += v;
        __syncthreads();
    }
    if (t < nbucket) {
        int excl = sc[t] - tot;
        bucket_start[t] = excl;
        int base = excl;
        #pragma unroll 8
        for (int b = 0; b < CSR_NBLK; ++b) {
            int c = hist_b[t * CSR_NBLK + b];
            hist_b[t * CSR_NBLK + b] = base;            // per-block scatter base
            base += c;
        }
    }
    if (t == 0) bucket_start[nbucket] = E;
}

// K2: scatter (src,dst) pairs into bucket-grouped tmp[], disjoint slots per block.
__global__ __launch_bounds__(1024) void bucket_scatter_kernel(const int* __restrict__ ei,
        const int* __restrict__ base_b, int2* __restrict__ tmp, int E, int nbucket, int chunk) {
    __shared__ int cur[512];
    const int b = blockIdx.x;
    for (int i = threadIdx.x; i < nbucket; i += blockDim.x)
        cur[i] = base_b[i * CSR_NBLK + b];
    __syncthreads();
    const int e0 = b * chunk, e1 = min(E, e0 + chunk);
    for (int e = e0 + (int)threadIdx.x; e < e1; e += blockDim.x) {
        int s = ei[e];
        int d = ei[E + e];
        int pos = atomicAdd(&cur[d >> 8], 1);           // LDS atomic
        tmp[pos] = make_int2(s, d);
    }
}

// K3: one block per bucket. LDS 256-bin histogram + scan -> rowptr/dinv/colidx.
__global__ __launch_bounds__(256) void csr_build_kernel(const int2* __restrict__ tmp,
        const int* __restrict__ bucket_start, int* __restrict__ rowptr,
        float* __restrict__ dinv, int* __restrict__ colidx, int n, int E) {
    __shared__ int hist[256], sc[256], cur[256];
    const int h = blockIdx.x;
    const int t = (int)threadIdx.x;
    hist[t] = 0;
    __syncthreads();
    const int e0 = bucket_start[h], e1 = bucket_start[h + 1];
    for (int e = e0 + t; e < e1; e += 256)
        atomicAdd(&hist[tmp[e].y & 255], 1);            // LDS atomic
    __syncthreads();
    sc[t] = hist[t];
    __syncthreads();
    for (int off = 1; off < 256; off <<= 1) {           // inclusive scan
        int v = (t >= off) ? sc[t - off] : 0;
        __syncthreads();
        sc[t] += v;
        __syncthreads();
    }
    const int excl = sc[t] - hist[t];
    const int node = h * 256 + t;
    if (node < n) {
        rowptr[node] = e0 + excl;
        dinv[node] = rsqrtf((float)(hist[t] + 1));      // +1 self-loop
    }
    if (h == 0 && t == 0) rowptr[n] = E;
    cur[t] = excl;
    __syncthreads();
    for (int e = e0 + t; e < e1; e += 256) {
        int2 p = tmp[e];
        int pos = e0 + atomicAdd(&cur[p.y & 255], 1);   // LDS atomic
        colidx[pos] = p.x;
    }
}

// ---------------- fp32 tiled GEMM: out[M,N] = A[M,K] @ W[K,N] (+bias), fp32 or bf16 out ----

template<int K, int N, bool BIAS, bool OUT_BF16>
__global__ __launch_bounds__(256) void gemm_kernel(const float* __restrict__ A,
        const float* __restrict__ W, const float* __restrict__ bias,
        void* __restrict__ out_, int M) {
    __shared__ float As[16][68];   // [k][m], padded
    __shared__ float Bs[16][68];   // [k][n]
    const int bm = blockIdx.x * 64;
    const int bn = blockIdx.y * 64;
    const int tid = (int)threadIdx.x;
    const int tx = tid & 15;
    const int ty = tid >> 4;
    float acc[4][4] = {};
    for (int k0 = 0; k0 < K; k0 += 16) {
        {   // A tile: 64 rows x 16 k, float4-coalesced, stored transposed
            int m   = tid >> 2;
            int kk4 = (tid & 3) * 4;
            float4 v = make_float4(0.f, 0.f, 0.f, 0.f);
            if (bm + m < M)
                v = *(const float4*)&A[(size_t)(bm + m) * K + k0 + kk4];
            As[kk4 + 0][m] = v.x;
            As[kk4 + 1][m] = v.y;
            As[kk4 + 2][m] = v.z;
            As[kk4 + 3][m] = v.w;
        }
        {   // B tile: 16 k x 64 n
            int kk = tid >> 4;
            int n4 = (tid & 15) * 4;
            *(float4*)&Bs[kk][n4] = *(const float4*)&W[(size_t)(k0 + kk) * N + bn + n4];
        }
        __syncthreads();
        #pragma unroll
        for (int kk = 0; kk < 16; ++kk) {
            float4 a4 = *(const float4*)&As[kk][ty * 4];
            float4 b4 = *(const float4*)&Bs[kk][tx * 4];
            float a[4] = {a4.x, a4.y, a4.z, a4.w};
            float b[4] = {b4.x, b4.y, b4.z, b4.w};
            #pragma unroll
            for (int i = 0; i < 4; ++i)
                #pragma unroll
                for (int j = 0; j < 4; ++j)
                    acc[i][j] += a[i] * b[j];
        }
        __syncthreads();
    }
    #pragma unroll
    for (int i = 0; i < 4; ++i) {
        int m = bm + ty * 4 + i;
        if (m >= M) continue;
        float v[4];
        #pragma unroll
        for (int j = 0; j < 4; ++j) {
            v[j] = acc[i][j];
            if (BIAS) v[j] += bias[bn + tx * 4 + j];
        }
        size_t base = (size_t)m * N + bn + tx * 4;
        if constexpr (OUT_BF16) {
            __hip_bfloat16* ob = (__hip_bfloat16*)out_;
            __hip_bfloat162 p0, p1;
            p0.x = __float2bfloat16(v[0]); p0.y = __float2bfloat16(v[1]);
            p1.x = __float2bfloat16(v[2]); p1.y = __float2bfloat16(v[3]);
            *(__hip_bfloat162*)&ob[base]     = p0;
            *(__hip_bfloat162*)&ob[base + 2] = p1;
        } else {
            float* of = (float*)out_;
            *(float2*)&of[base]     = make_float2(v[0], v[1]);
            *(float2*)&of[base + 2] = make_float2(v[2], v[3]);
        }
    }
}

// ---------------- CSR gather-aggregate, bf16 gather operand ----------------
// out[i] = dinv[i]*(sum_e dinv[s]*in_bf16[s] + dinv[i]*in_bf16[i]) [+bias] [relu]
// One wave per node (64 lanes); D=128 -> bf16x2 per lane, D=64 -> bf16 per lane.

template<int D, bool BIAS, bool RELU, bool OUT_BF16>
__global__ __launch_bounds__(256) void agg_kernel(const void* __restrict__ in_,
        const float* __restrict__ bias,
        const int* __restrict__ rowptr, const int* __restrict__ colidx,
        const float* __restrict__ dinv, void* __restrict__ out_, int n) {
    constexpr int VPL = D / 64;   // values per lane: 2 (D=128) or 1 (D=64)
    const int lane = (int)threadIdx.x & 63;
    const int wid  = (int)threadIdx.x >> 6;
    const int i = blockIdx.x * 4 + wid;
    if (i >= n) return;
    const float di = dinv[i];
    float acc0 = 0.f, acc1 = 0.f;
    if constexpr (VPL == 2) {
        const __hip_bfloat162* in = (const __hip_bfloat162*)in_;
        __hip_bfloat162 sv = in[(size_t)i * 64 + lane];
        acc0 = di * __bfloat162float(sv.x);
        acc1 = di * __bfloat162float(sv.y);
    } else {
        const __hip_bfloat16* in = (const __hip_bfloat16*)in_;
        acc0 = di * __bfloat162float(in[(size_t)i * 64 + lane]);
    }
    int e = rowptr[i];
    const int e1 = rowptr[i + 1];
    for (; e + 8 <= e1; e += 8) {
        int s[8]; float w[8];
        #pragma unroll
        for (int j = 0; j < 8; ++j) s[j] = __builtin_amdgcn_readfirstlane(colidx[e + j]);
        #pragma unroll
        for (int j = 0; j < 8; ++j) w[j] = dinv[s[j]];
        if constexpr (VPL == 2) {
            const __hip_bfloat162* in = (const __hip_bfloat162*)in_;
            __hip_bfloat162 v[8];
            #pragma unroll
            for (int j = 0; j < 8; ++j) v[j] = in[(size_t)s[j] * 64 + lane];
            #pragma unroll
            for (int j = 0; j < 8; ++j) {
                acc0 += w[j] * __bfloat162float(v[j].x);
                acc1 += w[j] * __bfloat162float(v[j].y);
            }
        } else {
            const __hip_bfloat16* in = (const __hip_bfloat16*)in_;
            __hip_bfloat16 v[8];
            #pragma unroll
            for (int j = 0; j < 8; ++j) v[j] = in[(size_t)s[j] * 64 + lane];
            #pragma unroll
            for (int j = 0; j < 8; ++j) acc0 += w[j] * __bfloat162float(v[j]);
        }
    }
    for (; e < e1; ++e) {
        int s = __builtin_amdgcn_readfirstlane(colidx[e]);
        float w = dinv[s];
        if constexpr (VPL == 2) {
            const __hip_bfloat162* in = (const __hip_bfloat162*)in_;
            __hip_bfloat162 v = in[(size_t)s * 64 + lane];
            acc0 += w * __bfloat162float(v.x);
            acc1 += w * __bfloat162float(v.y);
        } else {
            const __hip_bfloat16* in = (const __hip_bfloat16*)in_;
            acc0 += w * __bfloat162float(in[(size_t)s * 64 + lane]);
        }
    }
    float v0 = di * acc0;
    float v1 = di * acc1;
    if constexpr (VPL == 2) {
        if (BIAS) { v0 += bias[2 * lane]; v1 += bias[2 * lane + 1]; }
        if (RELU) { v0 = fmaxf(v0, 0.f); v1 = fmaxf(v1, 0.f); }
        if constexpr (OUT_BF16) {
            __hip_bfloat162* ob = (__hip_bfloat162*)out_;
            __hip_bfloat162 p; p.x = __float2bfloat16(v0); p.y = __float2bfloat16(v1);
            ob[(size_t)i * 64 + lane] = p;
        } else {
            float2* of = (float2*)out_;
            of[(size_t)i * 64 + lane] = make_float2(v0, v1);
        }
    } else {
        if (BIAS) v0 += bias[lane];
        if (RELU) v0 = fmaxf(v0, 0.f);
        if constexpr (OUT_BF16) {
            __hip_bfloat16* ob = (__hip_bfloat16*)out_;
            ob[(size_t)i * 64 + lane] = __float2bfloat16(v0);
        } else {
            float* of = (float*)out_;
            of[(size_t)i * 64 + lane] = v0;
        }
    }
}

// ---------------- driver ----------------

extern "C" void kernel_launch(void* const* d_in, const int* in_sizes, int n_in,
                              void* d_out, int out_size, void* d_ws, size_t ws_size,
                              hipStream_t stream) {
    const float* x  = (const float*)d_in[0];
    const int*   ei = (const int*)d_in[1];
    const float* W1 = (const float*)d_in[2];
    const float* b1 = (const float*)d_in[3];
    const float* W2 = (const float*)d_in[4];
    const float* b2 = (const float*)d_in[5];
    const float* W3 = (const float*)d_in[6];
    const float* b3 = (const float*)d_in[7];

    const int IN = 128;
    const int n  = in_sizes[0] / IN;   // 50000
    const int E  = in_sizes[1] / 2;    // 800000

    char* ws = (char*)d_ws;
    size_t off = 0;
    auto alloc = [&](size_t bytes) {
        char* p = ws + off;
        off += (bytes + 255) & ~(size_t)255;
        return p;
    };
    __hip_bfloat16* hA_bf = (__hip_bfloat16*)alloc((size_t)n * 128 * 2);  // 12.8 MB (h1 pre-agg)
    float*          bufB  = (float*)alloc((size_t)n * 128 * 4);           // 25.6 MB (h1 post-agg)
    __hip_bfloat16* hC_bf = (__hip_bfloat16*)alloc((size_t)n * 64 * 2);   //  6.4 MB (h1@W2)
    __hip_bfloat16* hD_bf = (__hip_bfloat16*)alloc((size_t)n * 64 * 2);   //  6.4 MB (h2)
    float*          bufE  = (float*)alloc((size_t)n * 64 * 4);            // 12.8 MB (Agg(h2))
    int*   rowptr = (int*)  alloc(((size_t)n + 1) * sizeof(int));
    float* dinv   = (float*)alloc((size_t)n * sizeof(float));
    int*   colidx = (int*)  alloc((size_t)E * sizeof(int));               //  3.2 MB
    int2*  tmp    = (int2*) alloc((size_t)E * sizeof(int2));              //  6.4 MB
    int*   hist_b = (int*)  alloc((size_t)512 * CSR_NBLK * sizeof(int));  //  128 KB
    int*   bstart = (int*)  alloc(513 * sizeof(int));

    const int nbucket = ceil_div(n, 256);          // 196 (<= 512)
    const int chunk   = ceil_div(E, CSR_NBLK);

    // ---- CSR build: zero global atomics, 4 dispatches ----
    bucket_hist_kernel<<<CSR_NBLK, 1024, 0, stream>>>(ei, hist_b, E, nbucket, chunk);
    bucket_scan_kernel<<<1, 512, 0, stream>>>(hist_b, bstart, nbucket, E);
    bucket_scatter_kernel<<<CSR_NBLK, 1024, 0, stream>>>(ei, hist_b, tmp, E, nbucket, chunk);
    csr_build_kernel<<<nbucket, 256, 0, stream>>>(tmp, bstart, rowptr, dinv, colidx, n, E);

    // ---- Layer 1: h1 = relu(Agg(x @ W1) + b1)  (agg at 128, bf16 gather) ----
    dim3 g1(ceil_div(n, 64), 2);
    gemm_kernel<128, 128, false, true><<<g1, 256, 0, stream>>>(x, W1, nullptr, hA_bf, n);
    agg_kernel<128, true, true, false><<<ceil_div(n, 4), 256, 0, stream>>>(
        hA_bf, b1, rowptr, colidx, dinv, bufB, n);

    // ---- Layer 2: h2 = relu(Agg(h1 @ W2) + b2)  (transform first -> agg at 64, bf16) ----
    dim3 g2(ceil_div(n, 64), 1);
    gemm_kernel<128, 64, false, true><<<g2, 256, 0, stream>>>(bufB, W2, nullptr, hC_bf, n);
    agg_kernel<64, true, true, true><<<ceil_div(n, 4), 256, 0, stream>>>(
        hC_bf, b2, rowptr, colidx, dinv, hD_bf, n);

    // ---- Layer 3: out = Agg(h2) @ W3 + b3  (agg first at 64, bf16; Agg commutes with W) ----
    agg_kernel<64, false, false, false><<<ceil_div(n, 4), 256, 0, stream>>>(
        hD_bf, nullptr, rowptr, colidx, dinv, bufE, n);
    dim3 g3(ceil_div(n, 64), 2);
    gemm_kernel<64, 128, true, false><<<g3, 256, 0, stream>>>(bufE, W3, b3, d_out, n);
}